// Round 7
// baseline (93.035 us; speedup 1.0000x reference)
//
#include <hip/hip_runtime.h>

// Chamfer distance via MFMA: d_ij = |p|^2 + |t|^2 - 2 p.t packed into ONE
// v_mfma_f32_32x32x16_bf16 per 32x32 tile using K-slot packing (K=16):
//   coord c (x,y,z): A slots [ch,ch,cl,cl], B slots [qh,ql,qh,ql], q = -2t
//     -> (ch+cl)*(qh+ql) = -2 c_p * c_t  (exact products: bf16*bf16 fits fp32)
//   norms: A [n2h,n2l,1,1], B [1,1,n2h,n2l] -> |p|^2 + |t|^2
// hi/lo bf16 split gives ~16-bit effective mantissa -> |err| ~3e-5 << 6e-4 thr.
//
// v9: ONE-PASS dual direction. The N x N matrix is computed once
// (rows = predict, cols = target); dist1 = row-mins (as before), dist2 =
// col-mins extracted from the same MFMA results:
//   per tile, per lane: 15-fmin tree over the 16 D-regs (these are 16 rows
//   of column lane&31) + fmin with other strip + shfl_xor(32) to merge the
//   lg halves -> wave's 64-row col-min; stored to a per-wave LDS strip
//   (plain ds_write, each col visited once; no atomics, no in-loop barrier),
//   folded across the 4 waves after one __syncthreads into cpart[64][N].
// Halves MFMA / loads / iterations / prep vs v8 at ~equal total VALU.
// Regalloc ledger respected: 2 strips + 2 bufs per wave, transient temps.

typedef short s16x8 __attribute__((ext_vector_type(8)));
typedef float f32x16 __attribute__((ext_vector_type(16)));

static __device__ __forceinline__ unsigned short f2bf(float f) {
    unsigned u = __float_as_uint(f);
    unsigned r = (u + 0x7FFFu + ((u >> 16) & 1u)) >> 16;  // RNE
    return (unsigned short)r;
}
static __device__ __forceinline__ float bf2f(unsigned short h) {
    return __uint_as_float(((unsigned)h) << 16);
}
static __device__ __forceinline__ void split2(float v, unsigned short& h, unsigned short& l) {
    h = f2bf(v);
    l = f2bf(v - bf2f(h));
}
static __device__ __forceinline__ float colmin16(f32x16 v) {
    float a = fminf(v[0], v[1]),  b = fminf(v[2], v[3]);
    float c = fminf(v[4], v[5]),  d = fminf(v[6], v[7]);
    float e = fminf(v[8], v[9]),  f = fminf(v[10], v[11]);
    float g = fminf(v[12], v[13]), h = fminf(v[14], v[15]);
    return fminf(fminf(fminf(a, b), fminf(c, d)),
                 fminf(fminf(e, f), fminf(g, h)));
}

union Pack16 { unsigned short u[16]; uint4 v[2]; };

#define CG  16   // column groups (N/CG = 1024 cols per block)
#define NRB 64   // row blocks (N/256)
#define RB  32   // reduce blocks

// Build A-pack for predict points and B-pack for target points only
// (one-pass kernel needs no swapped-role packs); init the reduce ticket.
__global__ void prep_pack(const float* __restrict__ predict, const float* __restrict__ target,
                          unsigned short* __restrict__ ApP, unsigned short* __restrict__ BpT,
                          unsigned* __restrict__ ticket, int N)
{
    int i = blockIdx.x * blockDim.x + threadIdx.x;
    if (i == 0) *ticket = 0u;
    if (i >= 2 * N) return;
    const unsigned short one = f2bf(1.0f);

    if (i < N) {                 // predict -> A pack
        float x = predict[3*i], y = predict[3*i+1], z = predict[3*i+2];
        float n2 = __builtin_fmaf(x, x, __builtin_fmaf(y, y, z*z));
        unsigned short xh,xl,yh,yl,zh,zl,nh,nl;
        split2(x, xh, xl); split2(y, yh, yl); split2(z, zh, zl); split2(n2, nh, nl);
        Pack16 a;
        a.u[0]=xh; a.u[1]=xh; a.u[2]=xl; a.u[3]=xl;
        a.u[4]=yh; a.u[5]=yh; a.u[6]=yl; a.u[7]=yl;
        a.u[8]=zh; a.u[9]=zh; a.u[10]=zl; a.u[11]=zl;
        a.u[12]=nh; a.u[13]=nl; a.u[14]=one; a.u[15]=one;
        uint4* ad = (uint4*)(ApP + (size_t)i * 16);
        ad[0] = a.v[0]; ad[1] = a.v[1];
    } else {                     // target -> B pack
        int j = i - N;
        float x = target[3*j], y = target[3*j+1], z = target[3*j+2];
        float n2 = __builtin_fmaf(x, x, __builtin_fmaf(y, y, z*z));
        unsigned short nh,nl,qxh,qxl,qyh,qyl,qzh,qzl;
        split2(n2, nh, nl);
        split2(-2.0f*x, qxh, qxl); split2(-2.0f*y, qyh, qyl); split2(-2.0f*z, qzh, qzl);
        Pack16 b;
        b.u[0]=qxh; b.u[1]=qxl; b.u[2]=qxh; b.u[3]=qxl;
        b.u[4]=qyh; b.u[5]=qyl; b.u[6]=qyh; b.u[7]=qyl;
        b.u[8]=qzh; b.u[9]=qzl; b.u[10]=qzh; b.u[11]=qzl;
        b.u[12]=one; b.u[13]=one; b.u[14]=nh; b.u[15]=nl;
        uint4* bd = (uint4*)(BpT + (size_t)j * 16);
        bd[0] = b.v[0]; bd[1] = b.v[1];
    }
}

// Block: 256 threads (4 waves). Each wave owns 64 rows (2 strips of 32).
// Block covers predict rows [bx*256, +256) x target cols [cg*1024, +1024).
// B fragments straight from L2 (B pack = 512 KB, resident).
// Per 32x32 tile (one MFMA result f32x16 per strip):
//   row-min -> rm (register, shuffle-reduced at end, written to partials1)
//   col-min -> lane tree + shfl_xor(32) -> per-wave LDS strip cm[w]
__global__ __launch_bounds__(256, 4) void chamfer_main(
    const unsigned short* __restrict__ Ap, const unsigned short* __restrict__ Bp,
    float* __restrict__ partials1, float* __restrict__ cpart, int N)
{
    __shared__ float cm[4][1024];

    const int tid  = threadIdx.x;
    const int w    = tid >> 6;
    const int lane = tid & 63;
    const int lm   = lane & 31;     // MFMA row/col within tile
    const int lg   = lane >> 5;     // k-half (and C/D row-half)
    const int bx   = blockIdx.x;
    const int cg   = blockIdx.y;

    const int row0 = bx * 256 + w * 64;

    // A fragments (hoisted for the whole kernel): lane needs A[row][k=lg*8..+7]
    const uint4* A4 = (const uint4*)Ap;
    s16x8 a0 = __builtin_bit_cast(s16x8, A4[(size_t)(row0      + lm) * 2 + lg]);
    s16x8 a1 = __builtin_bit_cast(s16x8, A4[(size_t)(row0 + 32 + lm) * 2 + lg]);

    float rm0[16], rm1[16];
    #pragma unroll
    for (int r = 0; r < 16; ++r) { rm0[r] = 3.0e38f; rm1[r] = 3.0e38f; }

    const f32x16 zc = {0.f,0.f,0.f,0.f,0.f,0.f,0.f,0.f,0.f,0.f,0.f,0.f,0.f,0.f,0.f,0.f};

    const int npt = N / CG;               // 1024 cols per block
    const int NT  = npt / 32;             // 32 tiles
    const uint4* bp = (const uint4*)Bp + (size_t)cg * npt * 2 + lm * 2 + lg;
    float* cmw = cm[w];

    // Register double-buffer over PAIRS of tiles (stride per tile = 64 uint4).
    uint4 c0 = bp[0];
    uint4 c1 = bp[64];
    const uint4* bnext = bp + 128;

#define BODY(TT)                                                              \
    {                                                                         \
        s16x8 bA = __builtin_bit_cast(s16x8, c0);                             \
        s16x8 bB = __builtin_bit_cast(s16x8, c1);                             \
        f32x16 p0 = __builtin_amdgcn_mfma_f32_32x32x16_bf16(a0, bA, zc, 0,0,0);\
        f32x16 q0 = __builtin_amdgcn_mfma_f32_32x32x16_bf16(a0, bB, zc, 0,0,0);\
        f32x16 p1 = __builtin_amdgcn_mfma_f32_32x32x16_bf16(a1, bA, zc, 0,0,0);\
        f32x16 q1 = __builtin_amdgcn_mfma_f32_32x32x16_bf16(a1, bB, zc, 0,0,0);\
        _Pragma("unroll")                                                     \
        for (int r = 0; r < 16; ++r) {                                        \
            rm0[r] = fminf(fminf(rm0[r], p0[r]), q0[r]);                      \
            rm1[r] = fminf(fminf(rm1[r], p1[r]), q1[r]);                      \
        }                                                                     \
        float va = fminf(colmin16(p0), colmin16(p1));                         \
        va = fminf(va, __shfl_xor(va, 32, 64));                               \
        float vb = fminf(colmin16(q0), colmin16(q1));                         \
        vb = fminf(vb, __shfl_xor(vb, 32, 64));                               \
        if (lane < 32) {                                                      \
            cmw[(TT) * 32 + lm]      = va;                                    \
            cmw[(TT) * 32 + 32 + lm] = vb;                                    \
        }                                                                     \
    }

    int t = 0;
    for (; t < NT - 2; t += 2) {
        uint4 n0 = bnext[0];
        uint4 n1 = bnext[64];
        bnext += 128;
        BODY(t);
        c0 = n0; c1 = n1;
    }
    BODY(t);   // last pair, t == NT-2
#undef BODY

    // dist1: reduce row-mins across the 32 col-lanes of each half.
    #pragma unroll
    for (int m = 1; m <= 16; m <<= 1) {
        #pragma unroll
        for (int r = 0; r < 16; ++r) {
            rm0[r] = fminf(rm0[r], __shfl_xor(rm0[r], m, 64));
            rm1[r] = fminf(rm1[r], __shfl_xor(rm1[r], m, 64));
        }
    }
    // C/D layout (m74/m101): row = (r&3) + 8*(r>>2) + 4*lg, col = lane&31.
    float* __restrict__ pout = partials1 + (size_t)cg * N;
    #pragma unroll
    for (int r = 0; r < 16; ++r) {
        int rl = (r & 3) + 8 * (r >> 2) + 4 * lg;
        if (lm == r) {
            pout[row0 +      rl] = rm0[r];
            pout[row0 + 32 + rl] = rm1[r];
        }
    }

    // dist2: fold the 4 waves' per-col mins, write this row-block's slice.
    __syncthreads();
    float* __restrict__ crow = cpart + (size_t)bx * N + (size_t)cg * npt;
    for (int c = tid; c < npt; c += 256) {
        float m = fminf(fminf(cm[0][c], cm[1][c]), fminf(cm[2][c], cm[3][c]));
        crow[c] = m;
    }
}

// Single ticket-based reduce: RB blocks x 256 threads.
// dist1: min over CG partial arrays per row; dist2: min over NRB arrays per
// col; clamp at 0, double sum, last block folds and writes the mean.
__global__ void chamfer_reduce(const float* __restrict__ partials1,
                               const float* __restrict__ cpart,
                               double* __restrict__ bsum, unsigned* __restrict__ ticket,
                               float* __restrict__ out, int N)
{
    const int n4 = N >> 2;
    const float4* p4 = (const float4*)partials1;
    const float4* c4 = (const float4*)cpart;
    double acc = 0.0;
    for (int i = blockIdx.x * blockDim.x + threadIdx.x; i < n4;
         i += gridDim.x * blockDim.x) {
        float4 m = p4[i];
        #pragma unroll
        for (int g = 1; g < CG; ++g) {
            float4 v = p4[(size_t)g * n4 + i];
            m.x = fminf(m.x, v.x); m.y = fminf(m.y, v.y);
            m.z = fminf(m.z, v.z); m.w = fminf(m.w, v.w);
        }
        acc += (double)fmaxf(m.x, 0.0f) + (double)fmaxf(m.y, 0.0f)
             + (double)fmaxf(m.z, 0.0f) + (double)fmaxf(m.w, 0.0f);

        float4 mc = c4[i];
        for (int g = 1; g < NRB; ++g) {
            float4 v = c4[(size_t)g * n4 + i];
            mc.x = fminf(mc.x, v.x); mc.y = fminf(mc.y, v.y);
            mc.z = fminf(mc.z, v.z); mc.w = fminf(mc.w, v.w);
        }
        acc += (double)fmaxf(mc.x, 0.0f) + (double)fmaxf(mc.y, 0.0f)
             + (double)fmaxf(mc.z, 0.0f) + (double)fmaxf(mc.w, 0.0f);
    }
    for (int off = 32; off; off >>= 1)
        acc += __shfl_down(acc, off, 64);
    __shared__ double sacc[4];
    const int wave = threadIdx.x >> 6, lane = threadIdx.x & 63;
    if (lane == 0) sacc[wave] = acc;
    __syncthreads();

    __shared__ unsigned is_last;
    if (threadIdx.x == 0) {
        bsum[blockIdx.x] = sacc[0] + sacc[1] + sacc[2] + sacc[3];
        __threadfence();
        unsigned old = atomicAdd(ticket, 1u);
        is_last = (old == gridDim.x - 1u) ? 1u : 0u;
    }
    __syncthreads();
    if (!is_last) return;

    if (threadIdx.x == 0) {
        __threadfence();   // acquire other blocks' bsum
        double t = 0.0;
        for (int i = 0; i < RB; ++i) t += bsum[i];
        out[0] = (float)(t / (double)N);   // mean(dist1)+mean(dist2), N == M
    }
}

extern "C" void kernel_launch(void* const* d_in, const int* in_sizes, int n_in,
                              void* d_out, int out_size, void* d_ws, size_t ws_size,
                              hipStream_t stream) {
    const float* predict = (const float*)d_in[0];
    const float* target  = (const float*)d_in[1];
    const int N = in_sizes[0] / 3;   // 16384

    unsigned short* ws16 = (unsigned short*)d_ws;
    unsigned short* ApP = ws16;                                   // N*16 bf16
    unsigned short* BpT = ws16 + (size_t)1 * N * 16;              // N*16 bf16
    float* partials1 = (float*)(ws16 + (size_t)2 * N * 16);       // CG*N floats
    float* cpart = partials1 + (size_t)CG * N;                    // NRB*N floats
    double* bsum = (double*)(cpart + (size_t)NRB * N);            // RB doubles
    unsigned* ticket = (unsigned*)(bsum + RB);                    // 1 uint

    prep_pack<<<dim3((2 * N + 255) / 256), dim3(256), 0, stream>>>(
        predict, target, ApP, BpT, ticket, N);

    dim3 grid(N / 256, CG);   // 64 x 16 = 1024 blocks
    chamfer_main<<<grid, dim3(256), 0, stream>>>(ApP, BpT, partials1, cpart, N);

    chamfer_reduce<<<dim3(RB), dim3(256), 0, stream>>>(
        partials1, cpart, bsum, ticket, (float*)d_out, N);
}